// Round 5
// baseline (401.771 us; speedup 1.0000x reference)
//
#include <hip/hip_runtime.h>

#define B_ 8192
#define IN_ 1024
#define OUT_ 256
#define E_ 16
#define KTOP 3
#define H_ 512
#define MAXSLOTS 26624   // 24576 + 16*127 rounded up
#define NTILES 208       // MAXSLOTS / 128
#define HBLK 16          // scatterscan blocks
#define GBLK 512         // gating blocks (16 rows each)

typedef __bf16 bf16;
typedef __bf16 bf16x4 __attribute__((ext_vector_type(4)));
typedef __bf16 bf16x8 __attribute__((ext_vector_type(8)));
typedef float f32x4 __attribute__((ext_vector_type(4)));

// ================= stage1: gating(conflict-free wg planes) + W transposes + inits =================
// blocks [0,512): gating 16 rows each; [512,2560): W1t; [2560,3072): W2t;
// [3072,3176): row_ids=-1; 3176: zero_row + tile_expert=-1.
__global__ __launch_bounds__(256) void k_stage1(
    const float* __restrict__ x, const float* __restrict__ wg,
    const float* __restrict__ W1, const float* __restrict__ W2,
    bf16* __restrict__ xbf, int* __restrict__ top_idx, float* __restrict__ top_gate,
    int* __restrict__ partial,
    bf16* __restrict__ w1t, bf16* __restrict__ w2t,
    int* __restrict__ row_ids, bf16* __restrict__ zero_row, int* __restrict__ tile_expert) {
    __shared__ __align__(16) float smem[16448];  // 65.8 KB: wg planes (16 x 257 float4) / transpose tile
    __shared__ int lcnt[16];
    int bx = blockIdx.x;
    int t = threadIdx.x;
    if (bx < GBLK) {
        // ---- gating: 16 rows/block; wg staged as 16 planes [e4*4+jj][j4] of float4 ----
        // plane stride 257 float4s: writes 2-way (free), reads conflict-free.
        // swgT4[p*257 + j4] = wg4[j4*16 + jj*4 + e4], p = e4*4+jj.
        float4* swgT4 = (float4*)smem;
        const float4* wg4 = (const float4*)wg;
        if (t < 16) lcnt[t] = 0;
#pragma unroll
        for (int i = 0; i < 16; i++) {
            int p = (t & 3) * 4 + ((t >> 2) & 3);
            int slot = i * 16 + (t >> 4);
            swgT4[p * 257 + slot] = wg4[i * 256 + t];
        }
        __syncthreads();
        int wv = t >> 6, lane = t & 63;
#pragma unroll
        for (int pr = 0; pr < 2; ++pr) {
            int row = bx * 16 + wv * 4 + pr * 2;   // rows row, row+1
            const float4* xra = (const float4*)(x + (size_t)row * IN_);
            const float4* xrb = (const float4*)(x + (size_t)(row + 1) * IN_);
            float4 xa[4], xb4[4];
#pragma unroll
            for (int q = 0; q < 4; q++) { xa[q] = xra[lane + 64 * q]; xb4[q] = xrb[lane + 64 * q]; }
#pragma unroll
            for (int q = 0; q < 4; q++) {
                bf16x4 ca, cb;
                ca[0] = (bf16)xa[q].x; ca[1] = (bf16)xa[q].y; ca[2] = (bf16)xa[q].z; ca[3] = (bf16)xa[q].w;
                cb[0] = (bf16)xb4[q].x; cb[1] = (bf16)xb4[q].y; cb[2] = (bf16)xb4[q].z; cb[3] = (bf16)xb4[q].w;
                *(bf16x4*)(xbf + (size_t)row * IN_ + (size_t)(lane + 64 * q) * 4) = ca;
                *(bf16x4*)(xbf + (size_t)(row + 1) * IN_ + (size_t)(lane + 64 * q) * 4) = cb;
            }
            float acca[16], accb[16];
#pragma unroll
            for (int e = 0; e < 16; e++) { acca[e] = 0.f; accb[e] = 0.f; }
#pragma unroll
            for (int q = 0; q < 4; q++) {
                float sa[4] = {xa[q].x, xa[q].y, xa[q].z, xa[q].w};
                float sb[4] = {xb4[q].x, xb4[q].y, xb4[q].z, xb4[q].w};
#pragma unroll
                for (int jj = 0; jj < 4; jj++) {
#pragma unroll
                    for (int e4 = 0; e4 < 4; e4++) {
                        float4 w4 = swgT4[(e4 * 4 + jj) * 257 + lane + 64 * q];
                        acca[e4 * 4 + 0] += sa[jj] * w4.x;
                        acca[e4 * 4 + 1] += sa[jj] * w4.y;
                        acca[e4 * 4 + 2] += sa[jj] * w4.z;
                        acca[e4 * 4 + 3] += sa[jj] * w4.w;
                        accb[e4 * 4 + 0] += sb[jj] * w4.x;
                        accb[e4 * 4 + 1] += sb[jj] * w4.y;
                        accb[e4 * 4 + 2] += sb[jj] * w4.z;
                        accb[e4 * 4 + 3] += sb[jj] * w4.w;
                    }
                }
            }
#pragma unroll
            for (int e = 0; e < 16; e++) {
#pragma unroll
                for (int s = 32; s > 0; s >>= 1) {
                    acca[e] += __shfl_xor(acca[e], s, 64);
                    accb[e] += __shfl_xor(accb[e], s, 64);
                }
            }
            if (lane < 2) {
                float v[16];
#pragma unroll
                for (int e = 0; e < 16; e++) v[e] = lane ? accb[e] : acca[e];
                int rsel = row + lane;
                int idx[KTOP];
                float val[KTOP];
#pragma unroll
                for (int k = 0; k < KTOP; k++) {
                    int best = 0;
                    float bv = v[0];
                    for (int e = 1; e < 16; e++) {
                        if (v[e] > bv) { bv = v[e]; best = e; }
                    }
                    idx[k] = best; val[k] = bv; v[best] = -1e30f;
                }
                float e1 = __expf(val[1] - val[0]);
                float e2 = __expf(val[2] - val[0]);
                float inv = 1.f / (1.f + e1 + e2);
                float g[KTOP] = {inv, e1 * inv, e2 * inv};
#pragma unroll
                for (int k = 0; k < KTOP; k++) {
                    top_idx[rsel * KTOP + k] = idx[k];
                    top_gate[rsel * KTOP + k] = g[k];
                    atomicAdd(&lcnt[idx[k]], 1);
                }
            }
        }
        __syncthreads();
        if (t < 16) partial[bx * 16 + t] = lcnt[t];
        return;
    }
    if (bx >= 3072) {
        if (bx < 3176) {            // row_ids = -1 (104*256 == MAXSLOTS)
            row_ids[(bx - 3072) * 256 + t] = -1;
        } else {                    // zero_row + tile_expert
#pragma unroll
            for (int i = 0; i < 4; i++) zero_row[t * 4 + i] = (bf16)0.f;
            if (t < NTILES) tile_expert[t] = -1;
        }
        return;
    }
    // ---- W transpose+convert: in [E][K][N] f32 -> out [E][N][K] bf16 ----
    float (*tile)[65] = (float(*)[65])smem;   // 16.6 KB
    const float* in; bf16* out; int Kd, Nd, e, tk, tn;
    if (bx < 2560) {            // W1: 16 experts x (16 x 8) tiles
        int b1x = bx - 512;
        in = W1; out = w1t; Kd = IN_; Nd = H_;
        e = b1x >> 7; int tt = b1x & 127; tk = tt >> 3; tn = tt & 7;
    } else {                    // W2: 16 experts x (8 x 4) tiles
        int b2x = bx - 2560;
        in = W2; out = w2t; Kd = H_; Nd = OUT_;
        e = b2x >> 5; int tt = b2x & 31; tk = tt >> 2; tn = tt & 3;
    }
    int r = t >> 6, c = t & 63;
    const float* src = in + ((size_t)e * Kd + tk * 64) * Nd + (size_t)tn * 64;
#pragma unroll
    for (int i = 0; i < 16; i++) {
        int rr = r + i * 4;
        tile[rr][c] = src[(size_t)rr * Nd + c];
    }
    __syncthreads();
    bf16* dst = out + ((size_t)e * Nd + tn * 64) * Kd + (size_t)tk * 64;
#pragma unroll
    for (int i = 0; i < 16; i++) {
        int rr = r + i * 4;
        dst[(size_t)rr * Kd + c] = (bf16)tile[c][rr];
    }
}

// ---------------- scatterscan: scan of 512x16 partials + scatter, 16 blocks ----------------
__global__ __launch_bounds__(256) void k_scatterscan(
    const int* __restrict__ top_idx, const float* __restrict__ top_gate,
    const int* __restrict__ partial,
    int* __restrict__ counts, int* __restrict__ tile_expert,
    int* __restrict__ row_ids, int* __restrict__ rowslot,
    float* __restrict__ partial_imp) {
    __shared__ int segsum[16][16];   // [seg][e]
    __shared__ int tote[16];
    __shared__ int sbase[16];
    __shared__ int lcnt[16];
    __shared__ float limp[16];
    int t = threadIdx.x;
    int blk = blockIdx.x;
    int e = t & 15, seg = t >> 4;    // 16 segs x (GBLK/16) gating-chunks each
    int s = 0;
#pragma unroll
    for (int i = 0; i < GBLK / 16; i++) s += partial[(seg * (GBLK / 16) + i) * 16 + e];
    segsum[seg][e] = s;
    if (t < 16) { lcnt[t] = 0; limp[t] = 0.f; }
    __syncthreads();
    if (t < 16) {
        int total = 0, pre = 0;
        for (int sg = 0; sg < 16; sg++) {
            int v = segsum[sg][t];
            total += v;
            if (sg < blk) pre += v;
        }
        tote[t] = total;
        segsum[0][t] = pre;
    }
    __syncthreads();
    if (t < 16) {
        int off = 0;
        for (int ee = 0; ee < 16; ee++) {
            if (ee == t) break;
            off += (tote[ee] + 127) & ~127;
        }
        sbase[t] = off + segsum[0][t];
        if (blk == 0) {
            counts[t] = tote[t];
            int pd = (tote[t] + 127) & ~127;
            for (int tt = off >> 7; tt < (off + pd) >> 7; ++tt) tile_expert[tt] = t;
        }
    }
    __syncthreads();
#pragma unroll
    for (int j = 0; j < 6; j++) {
        int gid = blk * 1536 + j * 256 + t;
        int ee = top_idx[gid];
        float g = top_gate[gid];
        int rank = atomicAdd(&lcnt[ee], 1);
        atomicAdd(&limp[ee], g);
        int slot = sbase[ee] + rank;
        row_ids[slot] = gid / KTOP;
        rowslot[gid] = slot;
    }
    __syncthreads();
    if (t < 16) partial_imp[blk * 16 + t] = limp[t];
}

// ---------------- FUSED GEMM1+relu+GEMM2: direct global->VGPR fragments, no LDS staging ----------------
// A-frag for mfma_16x16x32 = 8 consecutive k of one row = one 16B load from row-major xbf/w1t/w2t.
// LDS holds only hs (64 KB). 4 barriers total per block (hs hand-off x 2 chunks).
// Source-level double-buffered frag prefetch; compiler handles all waitcnts (no other VMEM in flight).
__global__ __launch_bounds__(512, 2) void k_fused(
    const bf16* __restrict__ xbf, const bf16* __restrict__ w1t,
    const float* __restrict__ b1, const bf16* __restrict__ w2t,
    const float* __restrict__ b2, const int* __restrict__ row_ids,
    const int* __restrict__ tile_expert, const bf16* __restrict__ zero_row,
    bf16* __restrict__ eout) {
    int e = tile_expert[blockIdx.x];
    if (e < 0) return;
    int slot_base = blockIdx.x * 128;
    __shared__ __align__(16) bf16 hs[32768];     // 64 KB: h chunk [128][256], XOR-swizzled
    int t = threadIdx.x;
    int w = t >> 6, lane = t & 63;
    int wm = (w & 1) * 64, wn = (w >> 1) * 64;   // 8 waves: 2x4 grid of 64x64 sub-tiles
    int lm = lane & 15, lq = lane >> 4;
    // per-lane fragment base pointers (lane lm = row/col within 16, lq = k-octet)
    const bf16* pa[4];    // A rows (slots)
    const bf16* pb1[4];   // W1t rows (h cols)
    const bf16* pb2[4];   // W2t rows (out cols)
    int hrow[4], hx[4];
#pragma unroll
    for (int i = 0; i < 4; i++) {
        int ra = wm + i * 16 + lm;
        int rb = wn + i * 16 + lm;
        int rid = row_ids[slot_base + ra];
        pa[i] = ((rid >= 0) ? xbf + (size_t)rid * IN_ : zero_row) + lq * 8;
        pb1[i] = w1t + ((size_t)e * H_ + rb) * IN_ + lq * 8;
        pb2[i] = w2t + ((size_t)e * OUT_ + rb) * H_ + lq * 8;
        hrow[i] = ra * 32;
        hx[i] = ra & 7;
    }
    float rbias2[4];
#pragma unroll
    for (int ni = 0; ni < 4; ++ni) rbias2[ni] = b2[e * OUT_ + wn + ni * 16 + lm];

    f32x4 acc2[4][4] = {};
#pragma unroll 1
    for (int c = 0; c < 2; ++c) {
        size_t boff = (size_t)c * (256 * IN_);
        float rbias1[4];
#pragma unroll
        for (int ni = 0; ni < 4; ++ni) rbias1[ni] = b1[e * H_ + c * 256 + wn + ni * 16 + lm];
        // ---------- GEMM1: acc1 = A[128x1024] @ W1chunk^T, frags direct from global ----------
        f32x4 acc1[4][4] = {};
        bf16x8 fa[2][4], fb[2][4];
#pragma unroll
        for (int i = 0; i < 4; i++) {
            fa[0][i] = *(const bf16x8*)(pa[i]);
            fb[0][i] = *(const bf16x8*)(pb1[i] + boff);
        }
#pragma unroll
        for (int k = 0; k < 32; ++k) {
            int p = k & 1;
            if (k < 31) {
                int off = (k + 1) * 32;
#pragma unroll
                for (int i = 0; i < 4; i++) {
                    fa[p ^ 1][i] = *(const bf16x8*)(pa[i] + off);
                    fb[p ^ 1][i] = *(const bf16x8*)(pb1[i] + boff + off);
                }
            }
#pragma unroll
            for (int mi = 0; mi < 4; mi++)
#pragma unroll
                for (int ni = 0; ni < 4; ni++)
                    acc1[mi][ni] = __builtin_amdgcn_mfma_f32_16x16x32_bf16(fa[p][mi], fb[p][ni], acc1[mi][ni], 0, 0, 0);
        }
        __syncthreads();   // all waves done reading hs (previous chunk's G2)
        // ---------- epilogue: bias + relu -> hs (XOR-swizzled to match G2 A-frag reads) ----------
#pragma unroll
        for (int mi = 0; mi < 4; mi++) {
#pragma unroll
            for (int ni = 0; ni < 4; ni++) {
                int col = wn + ni * 16 + lm;
                float bias = rbias1[ni];
#pragma unroll
                for (int r = 0; r < 4; r++) {
                    int row = wm + mi * 16 + lq * 4 + r;
                    float v = acc1[mi][ni][r] + bias;
                    v = v > 0.f ? v : 0.f;
                    hs[row * 256 + (((col >> 3) ^ (row & 7)) << 3) + (col & 7)] = (bf16)v;
                }
            }
        }
        __syncthreads();   // hs visible
        // ---------- GEMM2: acc2 += hs[128x256] @ W2chunk, B2 frags direct from global ----------
        const bf16x8* Hv = (const bf16x8*)hs;
        bf16x8 ha[2][4], wb[2][4];
#pragma unroll
        for (int i = 0; i < 4; i++) {
            ha[0][i] = Hv[hrow[i] + (lq ^ hx[i])];
            wb[0][i] = *(const bf16x8*)(pb2[i] + c * 256);
        }
#pragma unroll
        for (int s = 0; s < 8; ++s) {
            int p = s & 1;
            if (s < 7) {
#pragma unroll
                for (int i = 0; i < 4; i++) {
                    ha[p ^ 1][i] = Hv[hrow[i] + (((s + 1) * 4 + lq) ^ hx[i])];
                    wb[p ^ 1][i] = *(const bf16x8*)(pb2[i] + c * 256 + (s + 1) * 32);
                }
            }
#pragma unroll
            for (int mi = 0; mi < 4; mi++)
#pragma unroll
                for (int ni = 0; ni < 4; ni++)
                    acc2[mi][ni] = __builtin_amdgcn_mfma_f32_16x16x32_bf16(ha[p][mi], wb[p][ni], acc2[mi][ni], 0, 0, 0);
        }
    }
    // ---------- eout epilogue ----------
#pragma unroll
    for (int mi = 0; mi < 4; mi++) {
#pragma unroll
        for (int ni = 0; ni < 4; ni++) {
            int colg = wn + ni * 16 + lm;
            float bias = rbias2[ni];
#pragma unroll
            for (int r = 0; r < 4; r++) {
                int rowl = wm + mi * 16 + lq * 4 + r;
                eout[(size_t)(slot_base + rowl) * OUT_ + colg] = (bf16)(acc2[mi][ni][r] + bias);
            }
        }
    }
}

// ---------------- combine + loss (R10-proven) ----------------
__global__ __launch_bounds__(256) void k_combine(
    const bf16* __restrict__ eout, const int* __restrict__ rowslot,
    const float* __restrict__ top_gate, float* __restrict__ y,
    const float* __restrict__ partial_imp, const int* __restrict__ counts,
    float* __restrict__ loss_out) {
    int t = threadIdx.x;
    if (blockIdx.x == B_ / 4) {  // loss block
        __shared__ float imp[16];
        if (t < 16) {
            float s = 0.f;
#pragma unroll
            for (int b = 0; b < HBLK; b++) s += partial_imp[b * 16 + t];
            imp[t] = s;
        }
        __syncthreads();
        if (t == 0) {
            float si = 0.f, sl = 0.f;
            for (int e = 0; e < E_; e++) { si += imp[e]; sl += (float)counts[e]; }
            float mi_ = si / (float)E_, ml_ = sl / (float)E_;
            float vi = 0.f, vl = 0.f;
            for (int e = 0; e < E_; e++) {
                float d = imp[e] - mi_; vi += d * d;
                float d2 = (float)counts[e] - ml_; vl += d2 * d2;
            }
            vi /= (float)(E_ - 1); vl /= (float)(E_ - 1);
            *loss_out = vi / (mi_ * mi_ + 1e-10f) + vl / (ml_ * ml_ + 1e-10f);
        }
        return;
    }
    int b = blockIdx.x * 4 + (t >> 6);
    int lane = t & 63;
    int s0 = rowslot[b * 3], s1 = rowslot[b * 3 + 1], s2 = rowslot[b * 3 + 2];
    float g0 = top_gate[b * 3], g1 = top_gate[b * 3 + 1], g2 = top_gate[b * 3 + 2];
    bf16x4 v0 = *(const bf16x4*)(eout + (size_t)s0 * OUT_ + lane * 4);
    bf16x4 v1 = *(const bf16x4*)(eout + (size_t)s1 * OUT_ + lane * 4);
    bf16x4 v2 = *(const bf16x4*)(eout + (size_t)s2 * OUT_ + lane * 4);
    float4 r;
    r.x = g0 * (float)v0[0] + g1 * (float)v1[0] + g2 * (float)v2[0];
    r.y = g0 * (float)v0[1] + g1 * (float)v1[1] + g2 * (float)v2[1];
    r.z = g0 * (float)v0[2] + g1 * (float)v1[2] + g2 * (float)v2[2];
    r.w = g0 * (float)v0[3] + g1 * (float)v1[3] + g2 * (float)v2[3];
    ((float4*)y)[(size_t)b * 64 + lane] = r;
}

extern "C" void kernel_launch(void* const* d_in, const int* in_sizes, int n_in,
                              void* d_out, int out_size, void* d_ws, size_t ws_size,
                              hipStream_t stream) {
    (void)in_sizes; (void)n_in; (void)out_size; (void)ws_size;
    const float* x = (const float*)d_in[0];
    const float* wgate = (const float*)d_in[1];
    const float* W1 = (const float*)d_in[2];
    const float* b1 = (const float*)d_in[3];
    const float* W2 = (const float*)d_in[4];
    const float* b2 = (const float*)d_in[5];
    float* y = (float*)d_out;  // [B*OUT] floats, then loss scalar at [B*OUT]

    char* p = (char*)d_ws;
    auto alloc = [&](size_t bytes) {
        char* q = p;
        p += (bytes + 255) & ~(size_t)255;
        return q;
    };
    bf16* xbf = (bf16*)alloc((size_t)B_ * IN_ * 2);          // 16 MB (live through fused!)
    bf16* w1t = (bf16*)alloc((size_t)E_ * H_ * IN_ * 2);     // 16 MB
    bf16* w2t = (bf16*)alloc((size_t)E_ * OUT_ * H_ * 2);    // 4 MB
    bf16* eout = (bf16*)alloc((size_t)MAXSLOTS * OUT_ * 2);  // 13.6 MB
    int* row_ids = (int*)alloc((size_t)MAXSLOTS * 4);
    int* rowslot = (int*)alloc((size_t)B_ * KTOP * 4);
    int* top_idx = (int*)alloc((size_t)B_ * KTOP * 4);
    float* top_gate = (float*)alloc((size_t)B_ * KTOP * 4);
    int* counts = (int*)alloc(E_ * 4);
    int* partial = (int*)alloc((size_t)GBLK * E_ * 4);       // 32 KB gating hists
    float* partial_imp = (float*)alloc(HBLK * E_ * 4);
    int* tile_expert = (int*)alloc(NTILES * 4);
    bf16* zero_row = (bf16*)alloc(IN_ * 2);

    k_stage1<<<dim3(3177), dim3(256), 0, stream>>>(
        x, wgate, W1, W2, xbf, top_idx, top_gate, partial, w1t, w2t,
        row_ids, zero_row, tile_expert);
    k_scatterscan<<<dim3(HBLK), dim3(256), 0, stream>>>(
        top_idx, top_gate, partial, counts, tile_expert, row_ids, rowslot, partial_imp);
    k_fused<<<dim3(NTILES), dim3(512), 0, stream>>>(
        xbf, w1t, b1, w2t, b2, row_ids, tile_expert, zero_row, eout);
    k_combine<<<dim3(B_ / 4 + 1), dim3(256), 0, stream>>>(
        eout, rowslot, top_gate, y, partial_imp, counts, y + (size_t)B_ * OUT_);
}

// Round 6
// 233.752 us; speedup vs baseline: 1.7188x; 1.7188x over previous
//
#include <hip/hip_runtime.h>

#define B_ 8192
#define IN_ 1024
#define OUT_ 256
#define E_ 16
#define KTOP 3
#define H_ 512
#define MAXSLOTS 26624   // 24576 + 16*127 rounded up
#define NTILES 208       // MAXSLOTS / 128
#define HBLK 16          // scatterscan blocks
#define GBLK 512         // gating blocks (16 rows each)

typedef __bf16 bf16;
typedef __bf16 bf16x4 __attribute__((ext_vector_type(4)));
typedef __bf16 bf16x8 __attribute__((ext_vector_type(8)));
typedef float f32x4 __attribute__((ext_vector_type(4)));

// async global->LDS, 16B per lane. LDS dest must be wave-uniform base + lane*16.
__device__ __forceinline__ void async16(const bf16* g, bf16* l) {
    __builtin_amdgcn_global_load_lds(
        (const __attribute__((address_space(1))) void*)g,
        (__attribute__((address_space(3))) void*)l,
        16, 0, 0);
}

// ================= stage1: gating(conflict-free wg planes) + W transposes + inits =================
// blocks [0,512): gating 16 rows each; [512,2560): W1t; [2560,3072): W2t;
// [3072,3176): row_ids=-1; 3176: zero_row + tile_expert=-1.
__global__ __launch_bounds__(256) void k_stage1(
    const float* __restrict__ x, const float* __restrict__ wg,
    const float* __restrict__ W1, const float* __restrict__ W2,
    bf16* __restrict__ xbf, int* __restrict__ top_idx, float* __restrict__ top_gate,
    int* __restrict__ partial,
    bf16* __restrict__ w1t, bf16* __restrict__ w2t,
    int* __restrict__ row_ids, bf16* __restrict__ zero_row, int* __restrict__ tile_expert) {
    __shared__ __align__(16) float smem[16448];  // 65.8 KB: wg planes (16 x 257 float4) / transpose tile
    __shared__ int lcnt[16];
    int bx = blockIdx.x;
    int t = threadIdx.x;
    if (bx < GBLK) {
        // ---- gating: 16 rows/block; wg staged as 16 planes [e4*4+jj][j4] of float4 ----
        // plane stride 257 float4s: writes 2-way (free), reads conflict-free.
        // swgT4[p*257 + j4] = wg4[j4*16 + jj*4 + e4], p = e4*4+jj.
        float4* swgT4 = (float4*)smem;
        const float4* wg4 = (const float4*)wg;
        if (t < 16) lcnt[t] = 0;
#pragma unroll
        for (int i = 0; i < 16; i++) {
            int p = (t & 3) * 4 + ((t >> 2) & 3);
            int slot = i * 16 + (t >> 4);
            swgT4[p * 257 + slot] = wg4[i * 256 + t];
        }
        __syncthreads();
        int wv = t >> 6, lane = t & 63;
#pragma unroll
        for (int pr = 0; pr < 2; ++pr) {
            int row = bx * 16 + wv * 4 + pr * 2;   // rows row, row+1
            const float4* xra = (const float4*)(x + (size_t)row * IN_);
            const float4* xrb = (const float4*)(x + (size_t)(row + 1) * IN_);
            float4 xa[4], xb4[4];
#pragma unroll
            for (int q = 0; q < 4; q++) { xa[q] = xra[lane + 64 * q]; xb4[q] = xrb[lane + 64 * q]; }
#pragma unroll
            for (int q = 0; q < 4; q++) {
                bf16x4 ca, cb;
                ca[0] = (bf16)xa[q].x; ca[1] = (bf16)xa[q].y; ca[2] = (bf16)xa[q].z; ca[3] = (bf16)xa[q].w;
                cb[0] = (bf16)xb4[q].x; cb[1] = (bf16)xb4[q].y; cb[2] = (bf16)xb4[q].z; cb[3] = (bf16)xb4[q].w;
                *(bf16x4*)(xbf + (size_t)row * IN_ + (size_t)(lane + 64 * q) * 4) = ca;
                *(bf16x4*)(xbf + (size_t)(row + 1) * IN_ + (size_t)(lane + 64 * q) * 4) = cb;
            }
            float acca[16], accb[16];
#pragma unroll
            for (int e = 0; e < 16; e++) { acca[e] = 0.f; accb[e] = 0.f; }
#pragma unroll
            for (int q = 0; q < 4; q++) {
                float sa[4] = {xa[q].x, xa[q].y, xa[q].z, xa[q].w};
                float sb[4] = {xb4[q].x, xb4[q].y, xb4[q].z, xb4[q].w};
#pragma unroll
                for (int jj = 0; jj < 4; jj++) {
#pragma unroll
                    for (int e4 = 0; e4 < 4; e4++) {
                        float4 w4 = swgT4[(e4 * 4 + jj) * 257 + lane + 64 * q];
                        acca[e4 * 4 + 0] += sa[jj] * w4.x;
                        acca[e4 * 4 + 1] += sa[jj] * w4.y;
                        acca[e4 * 4 + 2] += sa[jj] * w4.z;
                        acca[e4 * 4 + 3] += sa[jj] * w4.w;
                        accb[e4 * 4 + 0] += sb[jj] * w4.x;
                        accb[e4 * 4 + 1] += sb[jj] * w4.y;
                        accb[e4 * 4 + 2] += sb[jj] * w4.z;
                        accb[e4 * 4 + 3] += sb[jj] * w4.w;
                    }
                }
            }
#pragma unroll
            for (int e = 0; e < 16; e++) {
#pragma unroll
                for (int s = 32; s > 0; s >>= 1) {
                    acca[e] += __shfl_xor(acca[e], s, 64);
                    accb[e] += __shfl_xor(accb[e], s, 64);
                }
            }
            if (lane < 2) {
                float v[16];
#pragma unroll
                for (int e = 0; e < 16; e++) v[e] = lane ? accb[e] : acca[e];
                int rsel = row + lane;
                int idx[KTOP];
                float val[KTOP];
#pragma unroll
                for (int k = 0; k < KTOP; k++) {
                    int best = 0;
                    float bv = v[0];
                    for (int e = 1; e < 16; e++) {
                        if (v[e] > bv) { bv = v[e]; best = e; }
                    }
                    idx[k] = best; val[k] = bv; v[best] = -1e30f;
                }
                float e1 = __expf(val[1] - val[0]);
                float e2 = __expf(val[2] - val[0]);
                float inv = 1.f / (1.f + e1 + e2);
                float g[KTOP] = {inv, e1 * inv, e2 * inv};
#pragma unroll
                for (int k = 0; k < KTOP; k++) {
                    top_idx[rsel * KTOP + k] = idx[k];
                    top_gate[rsel * KTOP + k] = g[k];
                    atomicAdd(&lcnt[idx[k]], 1);
                }
            }
        }
        __syncthreads();
        if (t < 16) partial[bx * 16 + t] = lcnt[t];
        return;
    }
    if (bx >= 3072) {
        if (bx < 3176) {            // row_ids = -1 (104*256 == MAXSLOTS)
            row_ids[(bx - 3072) * 256 + t] = -1;
        } else {                    // zero_row + tile_expert
#pragma unroll
            for (int i = 0; i < 4; i++) zero_row[t * 4 + i] = (bf16)0.f;
            if (t < NTILES) tile_expert[t] = -1;
        }
        return;
    }
    // ---- W transpose+convert: in [E][K][N] f32 -> out [E][N][K] bf16 ----
    float (*tile)[65] = (float(*)[65])smem;   // 16.6 KB
    const float* in; bf16* out; int Kd, Nd, e, tk, tn;
    if (bx < 2560) {            // W1: 16 experts x (16 x 8) tiles
        int b1x = bx - 512;
        in = W1; out = w1t; Kd = IN_; Nd = H_;
        e = b1x >> 7; int tt = b1x & 127; tk = tt >> 3; tn = tt & 7;
    } else {                    // W2: 16 experts x (8 x 4) tiles
        int b2x = bx - 2560;
        in = W2; out = w2t; Kd = H_; Nd = OUT_;
        e = b2x >> 5; int tt = b2x & 31; tk = tt >> 2; tn = tt & 3;
    }
    int r = t >> 6, c = t & 63;
    const float* src = in + ((size_t)e * Kd + tk * 64) * Nd + (size_t)tn * 64;
#pragma unroll
    for (int i = 0; i < 16; i++) {
        int rr = r + i * 4;
        tile[rr][c] = src[(size_t)rr * Nd + c];
    }
    __syncthreads();
    bf16* dst = out + ((size_t)e * Nd + tn * 64) * Kd + (size_t)tk * 64;
#pragma unroll
    for (int i = 0; i < 16; i++) {
        int rr = r + i * 4;
        dst[(size_t)rr * Kd + c] = (bf16)tile[c][rr];
    }
}

// ---------------- scatterscan: scan of 512x16 partials + scatter, 16 blocks ----------------
__global__ __launch_bounds__(256) void k_scatterscan(
    const int* __restrict__ top_idx, const float* __restrict__ top_gate,
    const int* __restrict__ partial,
    int* __restrict__ counts, int* __restrict__ tile_expert,
    int* __restrict__ row_ids, int* __restrict__ rowslot,
    float* __restrict__ partial_imp) {
    __shared__ int segsum[16][16];   // [seg][e]
    __shared__ int tote[16];
    __shared__ int sbase[16];
    __shared__ int lcnt[16];
    __shared__ float limp[16];
    int t = threadIdx.x;
    int blk = blockIdx.x;
    int e = t & 15, seg = t >> 4;    // 16 segs x (GBLK/16) gating-chunks each
    int s = 0;
#pragma unroll
    for (int i = 0; i < GBLK / 16; i++) s += partial[(seg * (GBLK / 16) + i) * 16 + e];
    segsum[seg][e] = s;
    if (t < 16) { lcnt[t] = 0; limp[t] = 0.f; }
    __syncthreads();
    if (t < 16) {
        int total = 0, pre = 0;
        for (int sg = 0; sg < 16; sg++) {
            int v = segsum[sg][t];
            total += v;
            if (sg < blk) pre += v;
        }
        tote[t] = total;
        segsum[0][t] = pre;
    }
    __syncthreads();
    if (t < 16) {
        int off = 0;
        for (int ee = 0; ee < 16; ee++) {
            if (ee == t) break;
            off += (tote[ee] + 127) & ~127;
        }
        sbase[t] = off + segsum[0][t];
        if (blk == 0) {
            counts[t] = tote[t];
            int pd = (tote[t] + 127) & ~127;
            for (int tt = off >> 7; tt < (off + pd) >> 7; ++tt) tile_expert[tt] = t;
        }
    }
    __syncthreads();
#pragma unroll
    for (int j = 0; j < 6; j++) {
        int gid = blk * 1536 + j * 256 + t;
        int ee = top_idx[gid];
        float g = top_gate[gid];
        int rank = atomicAdd(&lcnt[ee], 1);
        atomicAdd(&limp[ee], g);
        int slot = sbase[ee] + rank;
        row_ids[slot] = gid / KTOP;
        rowslot[gid] = slot;
    }
    __syncthreads();
    if (t < 16) partial_imp[blk * 16 + t] = limp[t];
}

// ---------------- FUSED GEMM1+relu+GEMM2: B via LDS depth-2 counted-vmcnt, A direct global->VGPR ----------------
// Per G1 step: A-frags = per-lane 16B row slices loaded straight from xbf (L1/L2-served, fa0/fa1
// ping-pong, +32 VGPR); B staged in 3 rotating 16 KB LDS buffers (2 async16/thread, uniform).
// LDS traffic/step: 48 KB (was 88). vmcnt: steady VWAIT(2); c0->c1 hand-off VWAIT(6); final VWAIT(0).
#define VWAIT(N) asm volatile("s_waitcnt vmcnt(" #N ")" ::: "memory")
#define BARR do { __builtin_amdgcn_s_barrier(); __builtin_amdgcn_sched_barrier(0); } while (0)
#define ROT do { bf16* _tmp = bA; bA = bB; bB = bC; bC = _tmp; } while (0)
#define LOADA(DST, K) do { \
    _Pragma("unroll") for (int _i = 0; _i < 4; _i++) \
        DST[_i] = *(const bf16x8*)(pa[_i] + (K) * 32); \
    __builtin_amdgcn_sched_barrier(0); \
} while (0)
#define G1STEP(BUF, FA) do { \
    const bf16x8* _Bv = (const bf16x8*)(BUF); \
    bf16x8 _bfv[4]; \
    _Pragma("unroll") for (int _i = 0; _i < 4; _i++) _bfv[_i] = _Bv[bidx[_i]]; \
    _Pragma("unroll") for (int _mi = 0; _mi < 4; _mi++) \
        _Pragma("unroll") for (int _ni = 0; _ni < 4; _ni++) \
            acc1[_mi][_ni] = __builtin_amdgcn_mfma_f32_16x16x32_bf16(FA[_mi], _bfv[_ni], acc1[_mi][_ni], 0, 0, 0); \
} while (0)
#define G2STEP(BUF, S) do { \
    const bf16x8* _Hv = (const bf16x8*)hs; \
    const bf16x8* _B2v = (const bf16x8*)(BUF); \
    bf16x8 _ha[4], _bfv[4]; \
    _Pragma("unroll") for (int _i = 0; _i < 4; _i++) { \
        _ha[_i] = _Hv[hrow[_i] + (((S) * 4 + lq) ^ hx[_i])]; \
        _bfv[_i] = _B2v[bidx[_i]]; \
    } \
    _Pragma("unroll") for (int _mi = 0; _mi < 4; _mi++) \
        _Pragma("unroll") for (int _ni = 0; _ni < 4; _ni++) \
            acc2[_mi][_ni] = __builtin_amdgcn_mfma_f32_16x16x32_bf16(_ha[_mi], _bfv[_ni], acc2[_mi][_ni], 0, 0, 0); \
} while (0)
__global__ __launch_bounds__(512, 2) void k_fused(
    const bf16* __restrict__ xbf, const bf16* __restrict__ w1t,
    const float* __restrict__ b1, const bf16* __restrict__ w2t,
    const float* __restrict__ b2, const int* __restrict__ row_ids,
    const int* __restrict__ tile_expert, const bf16* __restrict__ zero_row,
    bf16* __restrict__ eout) {
    int e = tile_expert[blockIdx.x];
    if (e < 0) return;
    int slot_base = blockIdx.x * 128;
    __shared__ __align__(16) bf16 smem[57344];   // 112 KB: hs 64 KB + 3 x 16 KB B-stage
    bf16* hs = smem;                             // 32768 elems
    bf16* bA = smem + 32768;
    bf16* bB = smem + 32768 + 8192;
    bf16* bC = smem + 32768 + 16384;
    int t = threadIdx.x;
    int cg = (t & 3) ^ ((t >> 3) & 3);           // pre-swizzled global k-vec for row m = t>>2
    const bf16* gB1[2];
    const bf16* gB2[2];
#pragma unroll
    for (int j = 0; j < 2; j++) {
        int m = j * 128 + (t >> 2);
        gB1[j] = w1t + ((size_t)e * H_ + m) * IN_ + cg * 8;     // + c*256*IN_ per chunk
        gB2[j] = w2t + ((size_t)e * OUT_ + m) * H_ + cg * 8;    // + c*256 + s*32
    }
    int w = t >> 6, lane = t & 63;
    int wm = (w & 1) * 64, wn = (w >> 1) * 64;   // 8 waves: 2x4 grid of 64x64 sub-tiles
    int lm = lane & 15, lq = lane >> 4;
    // A-frag direct pointers + B/hs LDS indices, loop-invariant
    const bf16* pa[4];
    int bidx[4], hrow[4], hx[4];
#pragma unroll
    for (int i = 0; i < 4; i++) {
        int ra = wm + i * 16 + lm;
        int rb = wn + i * 16 + lm;
        int rid = row_ids[slot_base + ra];
        pa[i] = ((rid >= 0) ? xbf + (size_t)rid * IN_ : zero_row) + lq * 8;
        bidx[i] = rb * 4 + (lq ^ ((rb >> 1) & 3));
        hrow[i] = ra * 32;
        hx[i] = ra & 7;
    }
    // bias preload + pin (keeps vmcnt accounting clean inside the loop)
    float rbias1[2][4], rbias2[4];
#pragma unroll
    for (int c2 = 0; c2 < 2; ++c2)
#pragma unroll
        for (int ni = 0; ni < 4; ++ni) rbias1[c2][ni] = b1[e * H_ + c2 * 256 + wn + ni * 16 + lm];
#pragma unroll
    for (int ni = 0; ni < 4; ++ni) rbias2[ni] = b2[e * OUT_ + wn + ni * 16 + lm];
#pragma unroll
    for (int c2 = 0; c2 < 2; ++c2)
#pragma unroll
        for (int ni = 0; ni < 4; ++ni) asm volatile("" : "+v"(rbias1[c2][ni]));
#pragma unroll
    for (int ni = 0; ni < 4; ++ni) asm volatile("" : "+v"(rbias2[ni]));

    auto stageB1 = [&](bf16* buf, int c, int k) {
        async16(gB1[0] + (size_t)c * (256 * IN_) + k * 32, buf + t * 8);
        async16(gB1[1] + (size_t)c * (256 * IN_) + k * 32, buf + (512 + t) * 8);
    };
    auto stageB2 = [&](bf16* buf, int c, int s) {
        async16(gB2[0] + c * 256 + s * 32, buf + t * 8);
        async16(gB2[1] + c * 256 + s * 32, buf + (512 + t) * 8);
    };

    f32x4 acc2[4][4] = {};
    bf16x8 fa0[4], fa1[4];
    // prologue: order [S(0), A(0), S(1)] -> entering k=0: VWAIT(2) leaves S(1)
    stageB1(bA, 0, 0);
    LOADA(fa0, 0);
    stageB1(bB, 0, 1);
#pragma unroll
    for (int c = 0; c < 2; ++c) {
        f32x4 acc1[4][4] = {};
        for (int kk = 0; kk < 30; kk += 2) {
            // even step k=kk: consume bA + fa0; issue A(k+1)->fa1, S(k+2)->bC
            VWAIT(2); BARR;
            G1STEP(bA, fa0);
            LOADA(fa1, kk + 1);
            stageB1(bC, c, kk + 2);
            ROT;
            // odd step k=kk+1: consume bA + fa1; issue A(k+2)->fa0, S(k+3)->bC
            VWAIT(2); BARR;
            G1STEP(bA, fa1);
            LOADA(fa0, kk + 2);
            stageB1(bC, c, kk + 3);
            ROT;
        }
        // k=30: issue A(31)->fa1, first G2 stage
        VWAIT(2); BARR;
        G1STEP(bA, fa0);
        LOADA(fa1, 31);
        stageB2(bC, c, 0);
        ROT;
        // k=31: no A issue; second G2 stage
        VWAIT(2); BARR;
        G1STEP(bA, fa1);
        stageB2(bC, c, 1);
        ROT;
        // ---------- epilogue: bias + relu -> hs (XOR-swizzled to match G2 A-frag reads) ----------
#pragma unroll
        for (int mi = 0; mi < 4; mi++) {
#pragma unroll
            for (int ni = 0; ni < 4; ni++) {
                int col = wn + ni * 16 + lm;
                float bias = rbias1[c][ni];
#pragma unroll
                for (int r = 0; r < 4; r++) {
                    int row = wm + mi * 16 + lq * 4 + r;
                    float v = acc1[mi][ni][r] + bias;
                    v = v > 0.f ? v : 0.f;
                    hs[row * 256 + (((col >> 3) ^ (row & 7)) << 3) + (col & 7)] = (bf16)v;
                }
            }
        }
        asm volatile("s_waitcnt lgkmcnt(0)" ::: "memory");   // hs writes committed before barrier
        for (int s = 0; s < 6; ++s) {
            VWAIT(2); BARR;
            G2STEP(bA, s);
            stageB2(bC, c, s + 2);
            ROT;
        }
        // s=6: chunk hand-off — prefetch chunk1 A(0)->fa0 and first chunk1 B stage
        VWAIT(2); BARR;
        G2STEP(bA, 6);
        if (c == 0) {
            LOADA(fa0, 0);
            stageB1(bC, 1, 0);
        }
        ROT;
        // s=7: c0: [S(7),A_c1,S_c1k0] outstanding -> VWAIT(6); c1: final drain
        if (c == 0) { VWAIT(6); } else { VWAIT(0); }
        BARR;
        G2STEP(bA, 7);
        if (c == 0) stageB1(bC, 1, 1);
        ROT;
    }
    // ---------- eout epilogue ----------
#pragma unroll
    for (int mi = 0; mi < 4; mi++) {
#pragma unroll
        for (int ni = 0; ni < 4; ni++) {
            int colg = wn + ni * 16 + lm;
            float bias = rbias2[ni];
#pragma unroll
            for (int r = 0; r < 4; r++) {
                int rowl = wm + mi * 16 + lq * 4 + r;
                eout[(size_t)(slot_base + rowl) * OUT_ + colg] = (bf16)(acc2[mi][ni][r] + bias);
            }
        }
    }
}

// ---------------- combine + loss (R10-proven) ----------------
__global__ __launch_bounds__(256) void k_combine(
    const bf16* __restrict__ eout, const int* __restrict__ rowslot,
    const float* __restrict__ top_gate, float* __restrict__ y,
    const float* __restrict__ partial_imp, const int* __restrict__ counts,
    float* __restrict__ loss_out) {
    int t = threadIdx.x;
    if (blockIdx.x == B_ / 4) {  // loss block
        __shared__ float imp[16];
        if (t < 16) {
            float s = 0.f;
#pragma unroll
            for (int b = 0; b < HBLK; b++) s += partial_imp[b * 16 + t];
            imp[t] = s;
        }
        __syncthreads();
        if (t == 0) {
            float si = 0.f, sl = 0.f;
            for (int e = 0; e < E_; e++) { si += imp[e]; sl += (float)counts[e]; }
            float mi_ = si / (float)E_, ml_ = sl / (float)E_;
            float vi = 0.f, vl = 0.f;
            for (int e = 0; e < E_; e++) {
                float d = imp[e] - mi_; vi += d * d;
                float d2 = (float)counts[e] - ml_; vl += d2 * d2;
            }
            vi /= (float)(E_ - 1); vl /= (float)(E_ - 1);
            *loss_out = vi / (mi_ * mi_ + 1e-10f) + vl / (ml_ * ml_ + 1e-10f);
        }
        return;
    }
    int b = blockIdx.x * 4 + (t >> 6);
    int lane = t & 63;
    int s0 = rowslot[b * 3], s1 = rowslot[b * 3 + 1], s2 = rowslot[b * 3 + 2];
    float g0 = top_gate[b * 3], g1 = top_gate[b * 3 + 1], g2 = top_gate[b * 3 + 2];
    bf16x4 v0 = *(const bf16x4*)(eout + (size_t)s0 * OUT_ + lane * 4);
    bf16x4 v1 = *(const bf16x4*)(eout + (size_t)s1 * OUT_ + lane * 4);
    bf16x4 v2 = *(const bf16x4*)(eout + (size_t)s2 * OUT_ + lane * 4);
    float4 r;
    r.x = g0 * (float)v0[0] + g1 * (float)v1[0] + g2 * (float)v2[0];
    r.y = g0 * (float)v0[1] + g1 * (float)v1[1] + g2 * (float)v2[1];
    r.z = g0 * (float)v0[2] + g1 * (float)v1[2] + g2 * (float)v2[2];
    r.w = g0 * (float)v0[3] + g1 * (float)v1[3] + g2 * (float)v2[3];
    ((float4*)y)[(size_t)b * 64 + lane] = r;
}

extern "C" void kernel_launch(void* const* d_in, const int* in_sizes, int n_in,
                              void* d_out, int out_size, void* d_ws, size_t ws_size,
                              hipStream_t stream) {
    (void)in_sizes; (void)n_in; (void)out_size; (void)ws_size;
    const float* x = (const float*)d_in[0];
    const float* wgate = (const float*)d_in[1];
    const float* W1 = (const float*)d_in[2];
    const float* b1 = (const float*)d_in[3];
    const float* W2 = (const float*)d_in[4];
    const float* b2 = (const float*)d_in[5];
    float* y = (float*)d_out;  // [B*OUT] floats, then loss scalar at [B*OUT]

    char* p = (char*)d_ws;
    auto alloc = [&](size_t bytes) {
        char* q = p;
        p += (bytes + 255) & ~(size_t)255;
        return q;
    };
    bf16* xbf = (bf16*)alloc((size_t)B_ * IN_ * 2);          // 16 MB (live through fused!)
    bf16* w1t = (bf16*)alloc((size_t)E_ * H_ * IN_ * 2);     // 16 MB
    bf16* w2t = (bf16*)alloc((size_t)E_ * OUT_ * H_ * 2);    // 4 MB
    bf16* eout = (bf16*)alloc((size_t)MAXSLOTS * OUT_ * 2);  // 13.6 MB
    int* row_ids = (int*)alloc((size_t)MAXSLOTS * 4);
    int* rowslot = (int*)alloc((size_t)B_ * KTOP * 4);
    int* top_idx = (int*)alloc((size_t)B_ * KTOP * 4);
    float* top_gate = (float*)alloc((size_t)B_ * KTOP * 4);
    int* counts = (int*)alloc(E_ * 4);
    int* partial = (int*)alloc((size_t)GBLK * E_ * 4);       // 32 KB gating hists
    float* partial_imp = (float*)alloc(HBLK * E_ * 4);
    int* tile_expert = (int*)alloc(NTILES * 4);
    bf16* zero_row = (bf16*)alloc(IN_ * 2);

    k_stage1<<<dim3(3177), dim3(256), 0, stream>>>(
        x, wgate, W1, W2, xbf, top_idx, top_gate, partial, w1t, w2t,
        row_ids, zero_row, tile_expert);
    k_scatterscan<<<dim3(HBLK), dim3(256), 0, stream>>>(
        top_idx, top_gate, partial, counts, tile_expert, row_ids, rowslot, partial_imp);
    k_fused<<<dim3(NTILES), dim3(512), 0, stream>>>(
        xbf, w1t, b1, w2t, b2, row_ids, tile_expert, zero_row, eout);
    k_combine<<<dim3(B_ / 4 + 1), dim3(256), 0, stream>>>(
        eout, rowslot, top_gate, y, partial_imp, counts, y + (size_t)B_ * OUT_);
}

// Round 7
// 180.256 us; speedup vs baseline: 2.2289x; 1.2968x over previous
//
#include <hip/hip_runtime.h>

#define B_ 8192
#define IN_ 1024
#define OUT_ 256
#define E_ 16
#define KTOP 3
#define H_ 512
#define MAXSLOTS 26624   // 24576 + 16*127 rounded up
#define NTILES 208       // MAXSLOTS / 128
#define HBLK 16          // scatterscan blocks
#define GBLK 512         // gating blocks (16 rows each)

typedef __bf16 bf16;
typedef __bf16 bf16x4 __attribute__((ext_vector_type(4)));
typedef __bf16 bf16x8 __attribute__((ext_vector_type(8)));
typedef float f32x4 __attribute__((ext_vector_type(4)));

// async global->LDS, 16B per lane. LDS dest must be wave-uniform base + lane*16.
__device__ __forceinline__ void async16(const bf16* g, bf16* l) {
    __builtin_amdgcn_global_load_lds(
        (const __attribute__((address_space(1))) void*)g,
        (__attribute__((address_space(3))) void*)l,
        16, 0, 0);
}

// ================= stage1: gating(conflict-free wg planes) + W transposes + inits =================
// blocks [0,512): gating 16 rows each; [512,2560): W1t; [2560,3072): W2t;
// [3072,3176): row_ids=-1; 3176: zero_row + tile_expert=-1.
__global__ __launch_bounds__(256) void k_stage1(
    const float* __restrict__ x, const float* __restrict__ wg,
    const float* __restrict__ W1, const float* __restrict__ W2,
    bf16* __restrict__ xbf, int* __restrict__ top_idx, float* __restrict__ top_gate,
    int* __restrict__ partial,
    bf16* __restrict__ w1t, bf16* __restrict__ w2t,
    int* __restrict__ row_ids, bf16* __restrict__ zero_row, int* __restrict__ tile_expert) {
    __shared__ __align__(16) float smem[16448];  // 65.8 KB: wg planes (16 x 257 float4) / transpose tile
    __shared__ int lcnt[16];
    int bx = blockIdx.x;
    int t = threadIdx.x;
    if (bx < GBLK) {
        // ---- gating: 16 rows/block; wg staged as 16 planes [e4*4+jj][j4] of float4 ----
        // plane stride 257 float4s: writes 2-way (free), reads conflict-free.
        // swgT4[p*257 + j4] = wg4[j4*16 + jj*4 + e4], p = e4*4+jj.
        float4* swgT4 = (float4*)smem;
        const float4* wg4 = (const float4*)wg;
        if (t < 16) lcnt[t] = 0;
#pragma unroll
        for (int i = 0; i < 16; i++) {
            int p = (t & 3) * 4 + ((t >> 2) & 3);
            int slot = i * 16 + (t >> 4);
            swgT4[p * 257 + slot] = wg4[i * 256 + t];
        }
        __syncthreads();
        int wv = t >> 6, lane = t & 63;
#pragma unroll
        for (int pr = 0; pr < 2; ++pr) {
            int row = bx * 16 + wv * 4 + pr * 2;   // rows row, row+1
            const float4* xra = (const float4*)(x + (size_t)row * IN_);
            const float4* xrb = (const float4*)(x + (size_t)(row + 1) * IN_);
            float4 xa[4], xb4[4];
#pragma unroll
            for (int q = 0; q < 4; q++) { xa[q] = xra[lane + 64 * q]; xb4[q] = xrb[lane + 64 * q]; }
#pragma unroll
            for (int q = 0; q < 4; q++) {
                bf16x4 ca, cb;
                ca[0] = (bf16)xa[q].x; ca[1] = (bf16)xa[q].y; ca[2] = (bf16)xa[q].z; ca[3] = (bf16)xa[q].w;
                cb[0] = (bf16)xb4[q].x; cb[1] = (bf16)xb4[q].y; cb[2] = (bf16)xb4[q].z; cb[3] = (bf16)xb4[q].w;
                *(bf16x4*)(xbf + (size_t)row * IN_ + (size_t)(lane + 64 * q) * 4) = ca;
                *(bf16x4*)(xbf + (size_t)(row + 1) * IN_ + (size_t)(lane + 64 * q) * 4) = cb;
            }
            float acca[16], accb[16];
#pragma unroll
            for (int e = 0; e < 16; e++) { acca[e] = 0.f; accb[e] = 0.f; }
#pragma unroll
            for (int q = 0; q < 4; q++) {
                float sa[4] = {xa[q].x, xa[q].y, xa[q].z, xa[q].w};
                float sb[4] = {xb4[q].x, xb4[q].y, xb4[q].z, xb4[q].w};
#pragma unroll
                for (int jj = 0; jj < 4; jj++) {
#pragma unroll
                    for (int e4 = 0; e4 < 4; e4++) {
                        float4 w4 = swgT4[(e4 * 4 + jj) * 257 + lane + 64 * q];
                        acca[e4 * 4 + 0] += sa[jj] * w4.x;
                        acca[e4 * 4 + 1] += sa[jj] * w4.y;
                        acca[e4 * 4 + 2] += sa[jj] * w4.z;
                        acca[e4 * 4 + 3] += sa[jj] * w4.w;
                        accb[e4 * 4 + 0] += sb[jj] * w4.x;
                        accb[e4 * 4 + 1] += sb[jj] * w4.y;
                        accb[e4 * 4 + 2] += sb[jj] * w4.z;
                        accb[e4 * 4 + 3] += sb[jj] * w4.w;
                    }
                }
            }
#pragma unroll
            for (int e = 0; e < 16; e++) {
#pragma unroll
                for (int s = 32; s > 0; s >>= 1) {
                    acca[e] += __shfl_xor(acca[e], s, 64);
                    accb[e] += __shfl_xor(accb[e], s, 64);
                }
            }
            if (lane < 2) {
                float v[16];
#pragma unroll
                for (int e = 0; e < 16; e++) v[e] = lane ? accb[e] : acca[e];
                int rsel = row + lane;
                int idx[KTOP];
                float val[KTOP];
#pragma unroll
                for (int k = 0; k < KTOP; k++) {
                    int best = 0;
                    float bv = v[0];
                    for (int e = 1; e < 16; e++) {
                        if (v[e] > bv) { bv = v[e]; best = e; }
                    }
                    idx[k] = best; val[k] = bv; v[best] = -1e30f;
                }
                float e1 = __expf(val[1] - val[0]);
                float e2 = __expf(val[2] - val[0]);
                float inv = 1.f / (1.f + e1 + e2);
                float g[KTOP] = {inv, e1 * inv, e2 * inv};
#pragma unroll
                for (int k = 0; k < KTOP; k++) {
                    top_idx[rsel * KTOP + k] = idx[k];
                    top_gate[rsel * KTOP + k] = g[k];
                    atomicAdd(&lcnt[idx[k]], 1);
                }
            }
        }
        __syncthreads();
        if (t < 16) partial[bx * 16 + t] = lcnt[t];
        return;
    }
    if (bx >= 3072) {
        if (bx < 3176) {            // row_ids = -1 (104*256 == MAXSLOTS)
            row_ids[(bx - 3072) * 256 + t] = -1;
        } else {                    // zero_row + tile_expert
#pragma unroll
            for (int i = 0; i < 4; i++) zero_row[t * 4 + i] = (bf16)0.f;
            if (t < NTILES) tile_expert[t] = -1;
        }
        return;
    }
    // ---- W transpose+convert: in [E][K][N] f32 -> out [E][N][K] bf16 ----
    float (*tile)[65] = (float(*)[65])smem;   // 16.6 KB
    const float* in; bf16* out; int Kd, Nd, e, tk, tn;
    if (bx < 2560) {            // W1: 16 experts x (16 x 8) tiles
        int b1x = bx - 512;
        in = W1; out = w1t; Kd = IN_; Nd = H_;
        e = b1x >> 7; int tt = b1x & 127; tk = tt >> 3; tn = tt & 7;
    } else {                    // W2: 16 experts x (8 x 4) tiles
        int b2x = bx - 2560;
        in = W2; out = w2t; Kd = H_; Nd = OUT_;
        e = b2x >> 5; int tt = b2x & 31; tk = tt >> 2; tn = tt & 3;
    }
    int r = t >> 6, c = t & 63;
    const float* src = in + ((size_t)e * Kd + tk * 64) * Nd + (size_t)tn * 64;
#pragma unroll
    for (int i = 0; i < 16; i++) {
        int rr = r + i * 4;
        tile[rr][c] = src[(size_t)rr * Nd + c];
    }
    __syncthreads();
    bf16* dst = out + ((size_t)e * Nd + tn * 64) * Kd + (size_t)tk * 64;
#pragma unroll
    for (int i = 0; i < 16; i++) {
        int rr = r + i * 4;
        dst[(size_t)rr * Kd + c] = (bf16)tile[c][rr];
    }
}

// ---------------- scatterscan: scan of 512x16 partials + scatter, 16 blocks ----------------
__global__ __launch_bounds__(256) void k_scatterscan(
    const int* __restrict__ top_idx, const float* __restrict__ top_gate,
    const int* __restrict__ partial,
    int* __restrict__ counts, int* __restrict__ tile_expert,
    int* __restrict__ row_ids, int* __restrict__ rowslot,
    float* __restrict__ partial_imp) {
    __shared__ int segsum[16][16];   // [seg][e]
    __shared__ int tote[16];
    __shared__ int sbase[16];
    __shared__ int lcnt[16];
    __shared__ float limp[16];
    int t = threadIdx.x;
    int blk = blockIdx.x;
    int e = t & 15, seg = t >> 4;    // 16 segs x (GBLK/16) gating-chunks each
    int s = 0;
#pragma unroll
    for (int i = 0; i < GBLK / 16; i++) s += partial[(seg * (GBLK / 16) + i) * 16 + e];
    segsum[seg][e] = s;
    if (t < 16) { lcnt[t] = 0; limp[t] = 0.f; }
    __syncthreads();
    if (t < 16) {
        int total = 0, pre = 0;
        for (int sg = 0; sg < 16; sg++) {
            int v = segsum[sg][t];
            total += v;
            if (sg < blk) pre += v;
        }
        tote[t] = total;
        segsum[0][t] = pre;
    }
    __syncthreads();
    if (t < 16) {
        int off = 0;
        for (int ee = 0; ee < 16; ee++) {
            if (ee == t) break;
            off += (tote[ee] + 127) & ~127;
        }
        sbase[t] = off + segsum[0][t];
        if (blk == 0) {
            counts[t] = tote[t];
            int pd = (tote[t] + 127) & ~127;
            for (int tt = off >> 7; tt < (off + pd) >> 7; ++tt) tile_expert[tt] = t;
        }
    }
    __syncthreads();
#pragma unroll
    for (int j = 0; j < 6; j++) {
        int gid = blk * 1536 + j * 256 + t;
        int ee = top_idx[gid];
        float g = top_gate[gid];
        int rank = atomicAdd(&lcnt[ee], 1);
        atomicAdd(&limp[ee], g);
        int slot = sbase[ee] + rank;
        row_ids[slot] = gid / KTOP;
        rowslot[gid] = slot;
    }
    __syncthreads();
    if (t < 16) partial_imp[blk * 16 + t] = limp[t];
}

// ---------------- FUSED GEMM1+relu+GEMM2: depth-2 counted-vmcnt pipeline (R4-proven) ----------------
// + T1 XCD-chunked tile swizzle: 208 tiles = 8 XCDs x 26; same-expert tiles land on one XCD's L2.
// BK=32 uniform steps (3 async16/thread each; G2 stages padded to 3 via benign re-issue).
// LDS 136 KB: hs[128][256] (64 KB) + 3 rotating 24 KB buffers (As 8 KB @0, B1s 16 KB @4096;
// B2s 16 KB aliases @0). Per iter: vmcnt(3); s_barrier; compute(k); issue stage(k+2).
#define VWAIT(N) asm volatile("s_waitcnt vmcnt(" #N ")" ::: "memory")
__global__ __launch_bounds__(512) void k_fused(
    const bf16* __restrict__ xbf, const bf16* __restrict__ w1t,
    const float* __restrict__ b1, const bf16* __restrict__ w2t,
    const float* __restrict__ b2, const int* __restrict__ row_ids,
    const int* __restrict__ tile_expert, const bf16* __restrict__ zero_row,
    bf16* __restrict__ eout) {
    int bid = blockIdx.x;
    int tile = (bid & 7) * (NTILES / 8) + (bid >> 3);   // XCD-chunked bijection (208 = 8*26)
    int e = tile_expert[tile];
    if (e < 0) return;
    int slot_base = tile * 128;
    __shared__ __align__(16) bf16 smem[69632];   // 136 KB
    bf16* hs = smem;                             // 32768 elems
    bf16* pb0 = smem + 32768;
    bf16* pb1 = smem + 32768 + 12288;
    bf16* pb2 = smem + 32768 + 24576;
    int t = threadIdx.x;
    int cg = (t & 3) ^ ((t >> 3) & 3);           // pre-swizzled global k-vec for row m = t>>2
    int rid = row_ids[slot_base + (t >> 2)];
    const bf16* gA = ((rid >= 0) ? xbf + (size_t)rid * IN_ : zero_row) + cg * 8;
    const bf16* gB1[2];
    const bf16* gB2[2];
#pragma unroll
    for (int j = 0; j < 2; j++) {
        int m = j * 128 + (t >> 2);
        gB1[j] = w1t + ((size_t)e * H_ + m) * IN_ + cg * 8;     // + c*256*IN_ per chunk
        gB2[j] = w2t + ((size_t)e * OUT_ + m) * H_ + cg * 8;    // + c*256 + s*32
    }
    int w = t >> 6, lane = t & 63;
    int wm = (w & 1) * 64, wn = (w >> 1) * 64;   // 8 waves: 2x4 grid of 64x64 sub-tiles
    int lm = lane & 15, lq = lane >> 4;
    // fragment LDS indices (bf16x8 units), loop-invariant
    int aidx[4], bidx[4], hrow[4], hx[4];
#pragma unroll
    for (int i = 0; i < 4; i++) {
        int ra = wm + i * 16 + lm;
        int rb = wn + i * 16 + lm;
        aidx[i] = ra * 4 + (lq ^ ((ra >> 1) & 3));
        bidx[i] = rb * 4 + (lq ^ ((rb >> 1) & 3));
        hrow[i] = ra * 32;
        hx[i] = ra & 7;
    }
    // bias preload + pin (keeps vmcnt accounting clean inside the loop)
    float rbias1[2][4], rbias2[4];
#pragma unroll
    for (int c2 = 0; c2 < 2; ++c2)
#pragma unroll
        for (int ni = 0; ni < 4; ++ni) rbias1[c2][ni] = b1[e * H_ + c2 * 256 + wn + ni * 16 + lm];
#pragma unroll
    for (int ni = 0; ni < 4; ++ni) rbias2[ni] = b2[e * OUT_ + wn + ni * 16 + lm];
#pragma unroll
    for (int c2 = 0; c2 < 2; ++c2)
#pragma unroll
        for (int ni = 0; ni < 4; ++ni) asm volatile("" : "+v"(rbias1[c2][ni]));
#pragma unroll
    for (int ni = 0; ni < 4; ++ni) asm volatile("" : "+v"(rbias2[ni]));

    auto stageG1 = [&](bf16* buf, int c, int k) {
        async16(gA + k * 32, buf + t * 8);
        async16(gB1[0] + (size_t)c * (256 * IN_) + k * 32, buf + 4096 + t * 8);
        async16(gB1[1] + (size_t)c * (256 * IN_) + k * 32, buf + 4096 + (512 + t) * 8);
    };
    auto stageG2 = [&](bf16* buf, int c, int s) {
        const bf16* p0 = gB2[0] + c * 256 + s * 32;
        async16(p0, buf + t * 8);
        async16(gB2[1] + c * 256 + s * 32, buf + (512 + t) * 8);
        async16(p0, buf + t * 8);   // benign re-issue: uniform 3 loads per stage
    };

    f32x4 acc2[4][4] = {};
    bf16 *bufA = pb0, *bufB = pb1, *bufC = pb2;
    stageG1(bufA, 0, 0);
    stageG1(bufB, 0, 1);
#pragma unroll
    for (int c = 0; c < 2; ++c) {
        f32x4 acc1[4][4] = {};
        for (int k = 0; k < 32; ++k) {
            VWAIT(3);
            __builtin_amdgcn_s_barrier();
            __builtin_amdgcn_sched_barrier(0);
            const bf16x8* Av = (const bf16x8*)bufA;
            const bf16x8* Bv = (const bf16x8*)(bufA + 4096);
            bf16x8 af[4], bfv[4];
#pragma unroll
            for (int i = 0; i < 4; i++) af[i] = Av[aidx[i]];
#pragma unroll
            for (int i = 0; i < 4; i++) bfv[i] = Bv[bidx[i]];
#pragma unroll
            for (int mi = 0; mi < 4; mi++)
#pragma unroll
                for (int ni = 0; ni < 4; ni++)
                    acc1[mi][ni] = __builtin_amdgcn_mfma_f32_16x16x32_bf16(af[mi], bfv[ni], acc1[mi][ni], 0, 0, 0);
            if (k < 30) stageG1(bufC, c, k + 2);
            else        stageG2(bufC, c, k - 30);
            bf16* tmpb = bufA; bufA = bufB; bufB = bufC; bufC = tmpb;
        }
        // ---------- epilogue: bias + relu -> hs (XOR-swizzled to match G2 A-frag reads) ----------
#pragma unroll
        for (int mi = 0; mi < 4; mi++) {
#pragma unroll
            for (int ni = 0; ni < 4; ni++) {
                int col = wn + ni * 16 + lm;
                float bias = rbias1[c][ni];
#pragma unroll
                for (int r = 0; r < 4; r++) {
                    int row = wm + mi * 16 + lq * 4 + r;
                    float v = acc1[mi][ni][r] + bias;
                    v = v > 0.f ? v : 0.f;
                    hs[row * 256 + (((col >> 3) ^ (row & 7)) << 3) + (col & 7)] = (bf16)v;
                }
            }
        }
        asm volatile("s_waitcnt lgkmcnt(0)" ::: "memory");   // hs writes committed before barrier
#pragma unroll
        for (int s = 0; s < 8; ++s) {
            if (c == 1 && s == 7) { VWAIT(0); } else { VWAIT(3); }
            __builtin_amdgcn_s_barrier();
            __builtin_amdgcn_sched_barrier(0);
            const bf16x8* Hv = (const bf16x8*)hs;
            const bf16x8* B2v = (const bf16x8*)bufA;
            bf16x8 af[4], bfv[4];
#pragma unroll
            for (int i = 0; i < 4; i++) af[i] = Hv[hrow[i] + ((s * 4 + lq) ^ hx[i])];
#pragma unroll
            for (int i = 0; i < 4; i++) bfv[i] = B2v[bidx[i]];
#pragma unroll
            for (int mi = 0; mi < 4; mi++)
#pragma unroll
                for (int ni = 0; ni < 4; ni++)
                    acc2[mi][ni] = __builtin_amdgcn_mfma_f32_16x16x32_bf16(af[mi], bfv[ni], acc2[mi][ni], 0, 0, 0);
            if (s < 6)       stageG2(bufC, c, s + 2);
            else if (c == 0) stageG1(bufC, 1, s - 6);
            bf16* tmpb = bufA; bufA = bufB; bufB = bufC; bufC = tmpb;
        }
    }
    // ---------- eout epilogue ----------
#pragma unroll
    for (int mi = 0; mi < 4; mi++) {
#pragma unroll
        for (int ni = 0; ni < 4; ni++) {
            int colg = wn + ni * 16 + lm;
            float bias = rbias2[ni];
#pragma unroll
            for (int r = 0; r < 4; r++) {
                int rowl = wm + mi * 16 + lq * 4 + r;
                eout[(size_t)(slot_base + rowl) * OUT_ + colg] = (bf16)(acc2[mi][ni][r] + bias);
            }
        }
    }
}

// ---------------- combine + loss (R10-proven) ----------------
__global__ __launch_bounds__(256) void k_combine(
    const bf16* __restrict__ eout, const int* __restrict__ rowslot,
    const float* __restrict__ top_gate, float* __restrict__ y,
    const float* __restrict__ partial_imp, const int* __restrict__ counts,
    float* __restrict__ loss_out) {
    int t = threadIdx.x;
    if (blockIdx.x == B_ / 4) {  // loss block
        __shared__ float imp[16];
        if (t < 16) {
            float s = 0.f;
#pragma unroll
            for (int b = 0; b < HBLK; b++) s += partial_imp[b * 16 + t];
            imp[t] = s;
        }
        __syncthreads();
        if (t == 0) {
            float si = 0.f, sl = 0.f;
            for (int e = 0; e < E_; e++) { si += imp[e]; sl += (float)counts[e]; }
            float mi_ = si / (float)E_, ml_ = sl / (float)E_;
            float vi = 0.f, vl = 0.f;
            for (int e = 0; e < E_; e++) {
                float d = imp[e] - mi_; vi += d * d;
                float d2 = (float)counts[e] - ml_; vl += d2 * d2;
            }
            vi /= (float)(E_ - 1); vl /= (float)(E_ - 1);
            *loss_out = vi / (mi_ * mi_ + 1e-10f) + vl / (ml_ * ml_ + 1e-10f);
        }
        return;
    }
    int b = blockIdx.x * 4 + (t >> 6);
    int lane = t & 63;
    int s0 = rowslot[b * 3], s1 = rowslot[b * 3 + 1], s2 = rowslot[b * 3 + 2];
    float g0 = top_gate[b * 3], g1 = top_gate[b * 3 + 1], g2 = top_gate[b * 3 + 2];
    bf16x4 v0 = *(const bf16x4*)(eout + (size_t)s0 * OUT_ + lane * 4);
    bf16x4 v1 = *(const bf16x4*)(eout + (size_t)s1 * OUT_ + lane * 4);
    bf16x4 v2 = *(const bf16x4*)(eout + (size_t)s2 * OUT_ + lane * 4);
    float4 r;
    r.x = g0 * (float)v0[0] + g1 * (float)v1[0] + g2 * (float)v2[0];
    r.y = g0 * (float)v0[1] + g1 * (float)v1[1] + g2 * (float)v2[1];
    r.z = g0 * (float)v0[2] + g1 * (float)v1[2] + g2 * (float)v2[2];
    r.w = g0 * (float)v0[3] + g1 * (float)v1[3] + g2 * (float)v2[3];
    ((float4*)y)[(size_t)b * 64 + lane] = r;
}

extern "C" void kernel_launch(void* const* d_in, const int* in_sizes, int n_in,
                              void* d_out, int out_size, void* d_ws, size_t ws_size,
                              hipStream_t stream) {
    (void)in_sizes; (void)n_in; (void)out_size; (void)ws_size;
    const float* x = (const float*)d_in[0];
    const float* wgate = (const float*)d_in[1];
    const float* W1 = (const float*)d_in[2];
    const float* b1 = (const float*)d_in[3];
    const float* W2 = (const float*)d_in[4];
    const float* b2 = (const float*)d_in[5];
    float* y = (float*)d_out;  // [B*OUT] floats, then loss scalar at [B*OUT]

    char* p = (char*)d_ws;
    auto alloc = [&](size_t bytes) {
        char* q = p;
        p += (bytes + 255) & ~(size_t)255;
        return q;
    };
    bf16* xbf = (bf16*)alloc((size_t)B_ * IN_ * 2);          // 16 MB (live through fused!)
    bf16* w1t = (bf16*)alloc((size_t)E_ * H_ * IN_ * 2);     // 16 MB
    bf16* w2t = (bf16*)alloc((size_t)E_ * OUT_ * H_ * 2);    // 4 MB
    bf16* eout = (bf16*)alloc((size_t)MAXSLOTS * OUT_ * 2);  // 13.6 MB
    int* row_ids = (int*)alloc((size_t)MAXSLOTS * 4);
    int* rowslot = (int*)alloc((size_t)B_ * KTOP * 4);
    int* top_idx = (int*)alloc((size_t)B_ * KTOP * 4);
    float* top_gate = (float*)alloc((size_t)B_ * KTOP * 4);
    int* counts = (int*)alloc(E_ * 4);
    int* partial = (int*)alloc((size_t)GBLK * E_ * 4);       // 32 KB gating hists
    float* partial_imp = (float*)alloc(HBLK * E_ * 4);
    int* tile_expert = (int*)alloc(NTILES * 4);
    bf16* zero_row = (bf16*)alloc(IN_ * 2);

    k_stage1<<<dim3(3177), dim3(256), 0, stream>>>(
        x, wgate, W1, W2, xbf, top_idx, top_gate, partial, w1t, w2t,
        row_ids, zero_row, tile_expert);
    k_scatterscan<<<dim3(HBLK), dim3(256), 0, stream>>>(
        top_idx, top_gate, partial, counts, tile_expert, row_ids, rowslot, partial_imp);
    k_fused<<<dim3(NTILES), dim3(512), 0, stream>>>(
        xbf, w1t, b1, w2t, b2, row_ids, tile_expert, zero_row, eout);
    k_combine<<<dim3(B_ / 4 + 1), dim3(256), 0, stream>>>(
        eout, rowslot, top_gate, y, partial_imp, counts, y + (size_t)B_ * OUT_);
}